// Round 8
// baseline (305.566 us; speedup 1.0000x reference)
//
#include <hip/hip_runtime.h>
#include <stdint.h>

#define T_TOK 4096
#define Hd    1024
#define Id    512
#define NE    16
#define NSLOT 32
#define TOPK  4
#define ECAP  1024
#define MAXT  (NE * (ECAP/128))

typedef __bf16 bf16x8 __attribute__((ext_vector_type(8)));
typedef float  floatx4 __attribute__((ext_vector_type(4)));

#define WAIT_VM(n) asm volatile("s_waitcnt vmcnt(" #n ")" ::: "memory")

static __device__ __forceinline__ void wg_barrier(){
  asm volatile("" ::: "memory");
  __builtin_amdgcn_s_barrier();
  asm volatile("" ::: "memory");
}

static __device__ __forceinline__ unsigned short f2bf(float f){
  unsigned int u = __float_as_uint(f);
  u = u + 0x7fffu + ((u >> 16) & 1u);
  return (unsigned short)(u >> 16);
}

// bf16(hi_src) << 16 | bf16(lo_src), truncation rounding (hi halves via v_perm)
static __device__ __forceinline__ uint32_t bfpack(uint32_t hi_src, uint32_t lo_src){
  return __builtin_amdgcn_perm(hi_src, lo_src, 0x07060302u);
}

static __device__ __forceinline__ void load_lds16(const void* g, void* l){
  __builtin_amdgcn_global_load_lds((const __attribute__((address_space(1))) void*)g,
                                   (__attribute__((address_space(3))) void*)l, 16, 0, 0);
}

// ---------------- router: logits (8 tok x 8 slots per wave) + fused x->bf16 --------------
// R4 post-mortem: wave-per-token re-read ALL of rw per wave (512 MB L2, 128 loads/wave,
// 10% occ) -> 58 us latency-bound. Now each wave: 8 tokens x 8 slots, 64 indep acc
// chains, 64 loads/wave, rw L2 traffic 8x lower. Block = 4 waves covers 8 tok x 32 slot.
// Cross-lane: merging butterfly (63 shfl) -> lane l holds fully-reduced value index l
// (t = l>>3, s = l&7 with flat index t*8+s).
__global__ __launch_bounds__(256) void router_kernel(
    const float* __restrict__ x, const float* __restrict__ rw,
    unsigned short* __restrict__ xb, float* __restrict__ logits,
    int* __restrict__ cursors){
  const int tid = threadIdx.x;
  if (blockIdx.x == 0 && tid < NE) cursors[tid] = 0;
  const int lane = tid & 63, sg = tid >> 6;       // sg = slot group 0..3
  const int t0 = blockIdx.x * 8;
  const int l4 = lane * 4;

  float v[64];                                     // v[t*8+s], s within group
  #pragma unroll
  for (int i = 0; i < 64; ++i) v[i] = 0.f;

  #pragma unroll
  for (int c = 0; c < 4; ++c){
    const int h = c * 256 + l4;
    float4 xv[8];
    #pragma unroll
    for (int t = 0; t < 8; ++t)
      xv[t] = *(const float4*)(x + (size_t)(t0 + t) * Hd + h);
    if (sg == 0){
      #pragma unroll
      for (int t = 0; t < 8; ++t){
        ushort4 o;
        o.x = f2bf(xv[t].x); o.y = f2bf(xv[t].y);
        o.z = f2bf(xv[t].z); o.w = f2bf(xv[t].w);
        *(ushort4*)(xb + (size_t)(t0 + t) * Hd + h) = o;
      }
    }
    #pragma unroll
    for (int s = 0; s < 8; ++s){
      float4 rv = *(const float4*)(rw + (size_t)(sg * 8 + s) * Hd + h);
      #pragma unroll
      for (int t = 0; t < 8; ++t)
        v[t*8 + s] += xv[t].x*rv.x + xv[t].y*rv.y + xv[t].z*rv.z + xv[t].w*rv.w;
    }
  }

  // merging butterfly: after bit `off`, v[i] (i % 2off == 0) holds value
  // (i | (lane & (2off-1))) summed over lane-groups of size 2off.
  #pragma unroll
  for (int off = 1; off < 64; off <<= 1){
    #pragma unroll
    for (int i = 0; i < 64; i += 2*off){
      const int j = i + off;
      float send  = (lane & off) ? v[i] : v[j];
      float other = __shfl_xor(send, off);
      v[i] = ((lane & off) ? v[j] : v[i]) + other;
    }
  }
  // v[0] on lane l = full sum of flat index l: t = l>>3, s = l&7
  logits[(size_t)(t0 + (lane >> 3)) * NSLOT + sg * 8 + (lane & 7)] = v[0];
}

// ---------------- weight transpose: register-only 64x64 tiles, VGPR-lean ----------------
// Pure streaming kernel: ~151 MB traffic. No LDS, low VGPR -> full occupancy.
// (R6 lesson: fusing topk into this kernel coincided with an absmax failure; kept
// separate pending bisection.)
__global__ __launch_bounds__(256) void transpose_kernel(
    const float* __restrict__ wg, const float* __restrict__ wu,
    const float* __restrict__ wd,
    unsigned short* __restrict__ wgb, unsigned short* __restrict__ wub,
    unsigned short* __restrict__ wdb){
  const int tb = blockIdx.x;                // 0..6143
  const int tid = threadIdx.x;
  const float* src; unsigned short* dst; int R, C, rt, ct;
  const int arr = tb >> 11;                 // 0:wg 1:wu 2:wd (2048 tiles each)
  const int rem = tb & 2047;
  const int e  = rem >> 7;                  // 128 tiles/expert
  const int t2 = rem & 127;
  if (arr == 0)      { src = wg; dst = wgb; R = Hd; C = Id; rt = t2 >> 3; ct = t2 & 7;  }
  else if (arr == 1) { src = wu; dst = wub; R = Hd; C = Id; rt = t2 >> 3; ct = t2 & 7;  }
  else               { src = wd; dst = wdb; R = Id; C = Hd; rt = t2 >> 4; ct = t2 & 15; }
  const int r0 = rt * 64, c0 = ct * 64;
  const float* s = src + (size_t)e * R * C;
  unsigned short* d = dst + (size_t)e * R * C;
  const int r_idx = tid >> 4;               // 16 r-blocks x 4 rows
  const int c_idx = tid & 15;               // 16 c-blocks x 4 cols
  const int rr = r0 + r_idx * 4;
  const int cc = c0 + c_idx * 4;
  uint4 u0 = *(const uint4*)(s + (size_t)(rr + 0)*C + cc);
  uint4 u1 = *(const uint4*)(s + (size_t)(rr + 1)*C + cc);
  uint4 u2 = *(const uint4*)(s + (size_t)(rr + 2)*C + cc);
  uint4 u3 = *(const uint4*)(s + (size_t)(rr + 3)*C + cc);
  uint2 o;
  o.x = bfpack(u1.x, u0.x); o.y = bfpack(u3.x, u2.x);
  *(uint2*)(d + (size_t)(cc + 0)*R + rr) = o;
  o.x = bfpack(u1.y, u0.y); o.y = bfpack(u3.y, u2.y);
  *(uint2*)(d + (size_t)(cc + 1)*R + rr) = o;
  o.x = bfpack(u1.z, u0.z); o.y = bfpack(u3.z, u2.z);
  *(uint2*)(d + (size_t)(cc + 2)*R + rr) = o;
  o.x = bfpack(u1.w, u0.w); o.y = bfpack(u3.w, u2.w);
  *(uint2*)(d + (size_t)(cc + 3)*R + rr) = o;
}

// ---------------- softmax + bias + top-4 + direct row scatter + (out = zw*x) ----------------
__global__ __launch_bounds__(256) void topk_kernel(
    const float* __restrict__ logits, const float* __restrict__ bias,
    const float* __restrict__ x,
    int* __restrict__ cursors, int* __restrict__ rowmap, float* __restrict__ roww,
    float* __restrict__ out){
  __shared__ float szw[8];
  const int tid = threadIdx.x;
  if (tid < 8){
    const int t = blockIdx.x * 8 + tid;
    float sc[32], bsc[32];
    #pragma unroll
    for (int i = 0; i < 32; i += 4){
      float4 v = *(const float4*)(logits + (size_t)t*NSLOT + i);
      sc[i] = v.x; sc[i+1] = v.y; sc[i+2] = v.z; sc[i+3] = v.w;
    }
    float mx = sc[0];
    #pragma unroll
    for (int i = 1; i < 32; ++i) mx = fmaxf(mx, sc[i]);
    float sum = 0.f;
    #pragma unroll
    for (int i = 0; i < 32; ++i){ sc[i] = __expf(sc[i]-mx); sum += sc[i]; }
    float inv = 1.f / sum;
    #pragma unroll
    for (int i = 0; i < 32; ++i){ sc[i] *= inv; bsc[i] = sc[i] + bias[i]; }
    unsigned int chosen = 0;
    float zw = 0.f;
    #pragma unroll
    for (int k = 0; k < TOPK; ++k){
      float bv = -1e30f, bw = 0.f; int best = 0;
      #pragma unroll
      for (int i = 0; i < 32; ++i){
        float v = ((chosen >> i) & 1u) ? -1e30f : bsc[i];
        if (v > bv){ bv = v; best = i; bw = sc[i]; }
      }
      chosen |= (1u << best);
      if (best < NE){
        int pos = atomicAdd(&cursors[best], 1);
        rowmap[best*ECAP + pos] = t;
        roww[best*ECAP + pos]   = bw;
      } else zw += bw;
    }
    szw[tid] = zw;
  }
  __syncthreads();
  const int lane = tid & 63, wid = tid >> 6;
  const size_t base = (size_t)blockIdx.x * 8 * Hd;
  #pragma unroll
  for (int r0 = 0; r0 < 8; r0 += 4){
    int r = r0 + wid;
    float s = szw[r];
    const float4* xs = (const float4*)(x + base + (size_t)r*Hd);
    float4* os = (float4*)(out + base + (size_t)r*Hd);
    #pragma unroll
    for (int q = 0; q < 4; ++q){
      float4 v = xs[lane + q*64];
      float4 o; o.x = v.x*s; o.y = v.y*s; o.z = v.z*s; o.w = v.w*s;
      os[lane + q*64] = o;
    }
  }
}

// Map linear tile -> (expert, row-base e*ECAP, rows ne, m0). False if out of range.
static __device__ __forceinline__ bool tile_map(const int* __restrict__ counts, int tile,
                                                int& e, int& off, int& ne, int& m0){
  int cumT = 0; e = -1; ne = 0; m0 = 0;
  #pragma unroll
  for (int ee = 0; ee < NE; ++ee){
    int c = counts[ee];
    int nt = (c + 127) >> 7;
    bool here = (e < 0) && (tile < cumT + nt);
    if (here){ e = ee; ne = c; m0 = (tile - cumT) * 128; }
    cumT += nt;
  }
  off = (e >= 0) ? e * ECAP : 0;
  return e >= 0;
}

// ---------------- fused gate+up GEMM + SwiGLU (128x128, dbuf, glds) ----------------
// (256,2): 128 AGPR acc + ~90 VGPR ~ 220 regs/wave; 3 waves/SIMD cap=170 -> SPILLS
// (round-3 regression: WRITE_SIZE 243MB). Do not raise.
__global__ __launch_bounds__(256, 2) void gateup_kernel(
    const unsigned short* __restrict__ xb,
    const unsigned short* __restrict__ wgb,
    const unsigned short* __restrict__ wub,
    const int* __restrict__ counts,
    const int* __restrict__ rowmap,
    const float* __restrict__ roww,
    unsigned short* __restrict__ act){
  const int b = blockIdx.x;
  int e, off, ne, m0;
  if (!tile_map(counts, b >> 2, e, off, ne, m0)) return;
  const int n0 = (b & 3) * 128;

  __shared__ unsigned short sA [2][128*32];
  __shared__ unsigned short sBg[2][128*32];
  __shared__ unsigned short sBu[2][128*32];
  __shared__ int sT[128];

  const int tid = threadIdx.x, lane = tid & 63, wid = tid >> 6;
  if (tid < 128){ int r = m0 + tid; sT[tid] = rowmap[off + ((r < ne) ? r : 0)]; }
  __syncthreads();

  const int r_in = lane >> 2, seg = lane & 3;
  const int rt0 = wid*32 + r_in, rt1 = rt0 + 16;
  const size_t wbase = (size_t)e * Id * Hd;

  const unsigned short* pA0 = xb + (size_t)sT[rt0]*Hd + seg*8;
  const unsigned short* pA1 = xb + (size_t)sT[rt1]*Hd + seg*8;
  const unsigned short* pG0 = wgb + wbase + (size_t)(n0+rt0)*Hd + seg*8;
  const unsigned short* pG1 = wgb + wbase + (size_t)(n0+rt1)*Hd + seg*8;
  const unsigned short* pU0 = wub + wbase + (size_t)(n0+rt0)*Hd + seg*8;
  const unsigned short* pU1 = wub + wbase + (size_t)(n0+rt1)*Hd + seg*8;
  const int dA0 = wid*1024, dA1 = wid*1024 + 512;

  floatx4 accg[4][4], accu[4][4];
  #pragma unroll
  for (int i = 0; i < 4; ++i)
    #pragma unroll
    for (int j = 0; j < 4; ++j){
      floatx4 z = {0.f,0.f,0.f,0.f};
      accg[i][j] = z; accu[i][j] = z;
    }
  const int wm = (wid & 1) * 64, wn = (wid >> 1) * 64;
  const int fm = lane & 15, fq = lane >> 4;

  load_lds16(pA0, &sA[0][dA0]);  load_lds16(pA1, &sA[0][dA1]);
  load_lds16(pG0, &sBg[0][dA0]); load_lds16(pG1, &sBg[0][dA1]);
  load_lds16(pU0, &sBu[0][dA0]); load_lds16(pU1, &sBu[0][dA1]);

  #pragma unroll 2
  for (int kit = 0; kit < 32; ++kit){
    const int cur = kit & 1;
    if (kit < 31){
      const int nk = (kit+1)*32;
      const int nb = 1 - cur;
      load_lds16(pA0 + nk, &sA[nb][dA0]);  load_lds16(pA1 + nk, &sA[nb][dA1]);
      load_lds16(pG0 + nk, &sBg[nb][dA0]); load_lds16(pG1 + nk, &sBg[nb][dA1]);
      load_lds16(pU0 + nk, &sBu[nb][dA0]); load_lds16(pU1 + nk, &sBu[nb][dA1]);
      WAIT_VM(6);
    } else {
      WAIT_VM(0);
    }
    wg_barrier();
    bf16x8 av[4], bgv[4], buv[4];
    #pragma unroll
    for (int i = 0; i < 4; ++i)
      av[i] = *(const bf16x8*)(&sA[cur][(wm + i*16 + fm)*32 + fq*8]);
    #pragma unroll
    for (int j = 0; j < 4; ++j){
      bgv[j] = *(const bf16x8*)(&sBg[cur][(wn + j*16 + fm)*32 + fq*8]);
      buv[j] = *(const bf16x8*)(&sBu[cur][(wn + j*16 + fm)*32 + fq*8]);
    }
    #pragma unroll
    for (int i = 0; i < 4; ++i)
      #pragma unroll
      for (int j = 0; j < 4; ++j){
        accg[i][j] = __builtin_amdgcn_mfma_f32_16x16x32_bf16(av[i], bgv[j], accg[i][j], 0, 0, 0);
        accu[i][j] = __builtin_amdgcn_mfma_f32_16x16x32_bf16(av[i], buv[j], accu[i][j], 0, 0, 0);
      }
    wg_barrier();
  }

  #pragma unroll
  for (int i = 0; i < 4; ++i){
    #pragma unroll
    for (int r = 0; r < 4; ++r){
      int row = wm + i*16 + fq*4 + r;
      if (m0 + row < ne){
        float w = roww[off + m0 + row];
        size_t rb = (size_t)(off + m0 + row) * Id + n0;
        #pragma unroll
        for (int j = 0; j < 4; ++j){
          float g = accg[i][j][r];
          float u = accu[i][j][r];
          float a = (g / (1.f + __expf(-g))) * u * w;
          act[rb + wn + j*16 + fm] = f2bf(a);
        }
      }
    }
  }
}

// ---------------- down GEMM + atomic scatter (dbuf, glds, split-K x2) ----------------
// (256,4): 64 AGPR acc + ~60 VGPR = 124 <= 128 cap -> no spill.
// R5 post-mortem: ~512 active blocks = 2/CU = 17.5% occ, MfmaUtil 8% -> latency bound.
// Split-K x2 (K=512 -> 2x256): doubles blocks to ~1024 (4/CU, the LDS cap), traffic
// unchanged, epilogue already atomicAdd so partials merge for free.
// R6 bisect: this change alone (R6's topk/transpose fusion reverted). R7 = infra fail,
// resubmitted unchanged.
__global__ __launch_bounds__(256, 4) void down_kernel(
    const unsigned short* __restrict__ act,
    const unsigned short* __restrict__ wdb,
    const int* __restrict__ counts,
    const int* __restrict__ rowmap,
    float* __restrict__ out){
  const int b = blockIdx.x;
  int e, off, ne, m0;
  if (!tile_map(counts, b >> 4, e, off, ne, m0)) return;
  const int n0 = ((b >> 1) & 7) * 128;
  const int k0 = (b & 1) * 256;             // K-half

  __shared__ unsigned short sA[2][128*32];
  __shared__ unsigned short sB[2][128*32];
  __shared__ int sT[128];

  const int tid = threadIdx.x, lane = tid & 63, wid = tid >> 6;
  if (tid < 128){ int r = m0 + tid; sT[tid] = (r < ne) ? rowmap[off + r] : 0; }

  const int r_in = lane >> 2, seg = lane & 3;
  const int rt0 = wid*32 + r_in, rt1 = rt0 + 16;
  const int gr0 = off + ((m0 + rt0 < ne) ? (m0 + rt0) : 0);
  const int gr1 = off + ((m0 + rt1 < ne) ? (m0 + rt1) : 0);
  const size_t wbase = (size_t)e * Hd * Id;
  const unsigned short* pA0 = act + (size_t)gr0*Id + k0 + seg*8;
  const unsigned short* pA1 = act + (size_t)gr1*Id + k0 + seg*8;
  const unsigned short* pB0 = wdb + wbase + (size_t)(n0+rt0)*Id + k0 + seg*8;
  const unsigned short* pB1 = wdb + wbase + (size_t)(n0+rt1)*Id + k0 + seg*8;
  const int dA0 = wid*1024, dA1 = wid*1024 + 512;

  floatx4 acc[4][4];
  #pragma unroll
  for (int i = 0; i < 4; ++i)
    #pragma unroll
    for (int j = 0; j < 4; ++j){ floatx4 z = {0.f,0.f,0.f,0.f}; acc[i][j] = z; }
  const int wm = (wid & 1) * 64, wn = (wid >> 1) * 64;
  const int fm = lane & 15, fq = lane >> 4;

  load_lds16(pA0, &sA[0][dA0]); load_lds16(pA1, &sA[0][dA1]);
  load_lds16(pB0, &sB[0][dA0]); load_lds16(pB1, &sB[0][dA1]);

  #pragma unroll 2
  for (int kit = 0; kit < 8; ++kit){
    const int cur = kit & 1;
    if (kit < 7){
      const int nk = (kit+1)*32;
      const int nb = 1 - cur;
      load_lds16(pA0 + nk, &sA[nb][dA0]); load_lds16(pA1 + nk, &sA[nb][dA1]);
      load_lds16(pB0 + nk, &sB[nb][dA0]); load_lds16(pB1 + nk, &sB[nb][dA1]);
      WAIT_VM(4);
    } else {
      WAIT_VM(0);
    }
    wg_barrier();
    bf16x8 av[4], bv[4];
    #pragma unroll
    for (int i = 0; i < 4; ++i) av[i] = *(const bf16x8*)(&sA[cur][(wm + i*16 + fm)*32 + fq*8]);
    #pragma unroll
    for (int j = 0; j < 4; ++j) bv[j] = *(const bf16x8*)(&sB[cur][(wn + j*16 + fm)*32 + fq*8]);
    #pragma unroll
    for (int i = 0; i < 4; ++i)
      #pragma unroll
      for (int j = 0; j < 4; ++j)
        acc[i][j] = __builtin_amdgcn_mfma_f32_16x16x32_bf16(av[i], bv[j], acc[i][j], 0, 0, 0);
    wg_barrier();
  }

  #pragma unroll
  for (int i = 0; i < 4; ++i){
    #pragma unroll
    for (int r = 0; r < 4; ++r){
      int row = wm + i*16 + fq*4 + r;
      if (m0 + row < ne){
        int t = sT[row];
        #pragma unroll
        for (int j = 0; j < 4; ++j)
          atomicAdd(&out[(size_t)t*Hd + n0 + wn + j*16 + fm], acc[i][j][r]);
      }
    }
  }
}

// =================================================================
extern "C" void kernel_launch(void* const* d_in, const int* in_sizes, int n_in,
                              void* d_out, int out_size, void* d_ws, size_t ws_size,
                              hipStream_t stream){
  (void)in_sizes; (void)n_in; (void)out_size; (void)ws_size;
  const float* x    = (const float*)d_in[0];
  const float* rw   = (const float*)d_in[1];
  const float* bias = (const float*)d_in[2];
  const float* wg   = (const float*)d_in[3];
  const float* wu   = (const float*)d_in[4];
  const float* wd   = (const float*)d_in[5];
  float* out = (float*)d_out;

  char* ws = (char*)d_ws;
  const size_t WSZ = (size_t)NE * Id * Hd * 2;
  unsigned short* wgb = (unsigned short*)(ws);
  unsigned short* wub = (unsigned short*)(ws + WSZ);
  unsigned short* wdb = (unsigned short*)(ws + 2*WSZ);
  unsigned short* xb  = (unsigned short*)(ws + 3*WSZ);
  unsigned short* act = (unsigned short*)(ws + 3*WSZ + (size_t)T_TOK*Hd*2);
  char* misc = ws + 3*WSZ + (size_t)T_TOK*Hd*2 + (size_t)NE*ECAP*Id*2;

  const size_t LOGB = (size_t)T_TOK * NSLOT * 4;
  float* logits  = (float*)misc;
  int*   cursors = (int*)(misc + LOGB);
  char* p2 = misc + LOGB + 256;
  int*   rowmap = (int*)p2;                     p2 += (size_t)NE*ECAP*4;
  float* roww   = (float*)p2;

  router_kernel<<<T_TOK/8, 256, 0, stream>>>(x, rw, xb, logits, cursors);
  transpose_kernel<<<6144, 256, 0, stream>>>(wg, wu, wd, wgb, wub, wdb);
  topk_kernel<<<T_TOK/8, 256, 0, stream>>>(logits, bias, x, cursors, rowmap, roww, out);
  gateup_kernel<<<MAXT*4, 256, 0, stream>>>(xb, wgb, wub, cursors, rowmap, roww, act);
  down_kernel<<<MAXT*16, 256, 0, stream>>>(act, wdb, cursors, rowmap, out);
}

// Round 9
// 280.906 us; speedup vs baseline: 1.0878x; 1.0878x over previous
//
#include <hip/hip_runtime.h>
#include <stdint.h>

#define T_TOK 4096
#define Hd    1024
#define Id    512
#define NE    16
#define NSLOT 32
#define TOPK  4
#define ECAP  1024
#define MAXT  (NE * (ECAP/128))

typedef __bf16 bf16x8 __attribute__((ext_vector_type(8)));
typedef float  floatx4 __attribute__((ext_vector_type(4)));

#define WAIT_VM(n) asm volatile("s_waitcnt vmcnt(" #n ")" ::: "memory")

static __device__ __forceinline__ void wg_barrier(){
  asm volatile("" ::: "memory");
  __builtin_amdgcn_s_barrier();
  asm volatile("" ::: "memory");
}

static __device__ __forceinline__ unsigned short f2bf(float f){
  unsigned int u = __float_as_uint(f);
  u = u + 0x7fffu + ((u >> 16) & 1u);
  return (unsigned short)(u >> 16);
}

// bf16(hi_src) << 16 | bf16(lo_src), truncation rounding (hi halves via v_perm)
static __device__ __forceinline__ uint32_t bfpack(uint32_t hi_src, uint32_t lo_src){
  return __builtin_amdgcn_perm(hi_src, lo_src, 0x07060302u);
}

static __device__ __forceinline__ void load_lds16(const void* g, void* l){
  __builtin_amdgcn_global_load_lds((const __attribute__((address_space(1))) void*)g,
                                   (__attribute__((address_space(3))) void*)l, 16, 0, 0);
}

// ---------------- router: logits (8 tok x 8 slots per wave) + fused x->bf16 --------------
// R4 post-mortem: wave-per-token re-read ALL of rw per wave (512 MB L2, 128 loads/wave,
// 10% occ) -> 58 us latency-bound. Now each wave: 8 tokens x 8 slots, 64 indep acc
// chains, 64 loads/wave, rw L2 traffic 8x lower. Block = 4 waves covers 8 tok x 32 slot.
__global__ __launch_bounds__(256) void router_kernel(
    const float* __restrict__ x, const float* __restrict__ rw,
    unsigned short* __restrict__ xb, float* __restrict__ logits,
    int* __restrict__ cursors){
  const int tid = threadIdx.x;
  if (blockIdx.x == 0 && tid < NE) cursors[tid] = 0;
  const int lane = tid & 63, sg = tid >> 6;       // sg = slot group 0..3
  const int t0 = blockIdx.x * 8;
  const int l4 = lane * 4;

  float v[64];                                     // v[t*8+s], s within group
  #pragma unroll
  for (int i = 0; i < 64; ++i) v[i] = 0.f;

  #pragma unroll
  for (int c = 0; c < 4; ++c){
    const int h = c * 256 + l4;
    float4 xv[8];
    #pragma unroll
    for (int t = 0; t < 8; ++t)
      xv[t] = *(const float4*)(x + (size_t)(t0 + t) * Hd + h);
    if (sg == 0){
      #pragma unroll
      for (int t = 0; t < 8; ++t){
        ushort4 o;
        o.x = f2bf(xv[t].x); o.y = f2bf(xv[t].y);
        o.z = f2bf(xv[t].z); o.w = f2bf(xv[t].w);
        *(ushort4*)(xb + (size_t)(t0 + t) * Hd + h) = o;
      }
    }
    #pragma unroll
    for (int s = 0; s < 8; ++s){
      float4 rv = *(const float4*)(rw + (size_t)(sg * 8 + s) * Hd + h);
      #pragma unroll
      for (int t = 0; t < 8; ++t)
        v[t*8 + s] += xv[t].x*rv.x + xv[t].y*rv.y + xv[t].z*rv.z + xv[t].w*rv.w;
    }
  }

  // merging butterfly: after bit `off`, v[i] (i % 2off == 0) holds value
  // (i | (lane & (2off-1))) summed over lane-groups of size 2off.
  #pragma unroll
  for (int off = 1; off < 64; off <<= 1){
    #pragma unroll
    for (int i = 0; i < 64; i += 2*off){
      const int j = i + off;
      float send  = (lane & off) ? v[i] : v[j];
      float other = __shfl_xor(send, off);
      v[i] = ((lane & off) ? v[j] : v[i]) + other;
    }
  }
  // v[0] on lane l = full sum of flat index l: t = l>>3, s = l&7
  logits[(size_t)(t0 + (lane >> 3)) * NSLOT + sg * 8 + (lane & 7)] = v[0];
}

// ---------------- weight transpose: register-only 128x64 tiles, 64B store segments -----
// R8 post-mortem: old 4x4-block mapping gave 16x32B segments per store instruction ->
// transaction-rate bound at 2.2 TB/s (VALU 4%, occ 56%, not HBM-bound: weights are
// L3-resident). New 8-row x 4-col per thread: stores are uint4 (16B/lane) with 4
// consecutive r_idx lanes contiguous = 16x64B segments (full cache-line granule),
// half the store instructions. Loads unchanged (256B segments).
__global__ __launch_bounds__(256) void transpose_kernel(
    const float* __restrict__ wg, const float* __restrict__ wu,
    const float* __restrict__ wd,
    unsigned short* __restrict__ wgb, unsigned short* __restrict__ wub,
    unsigned short* __restrict__ wdb){
  const int tb = blockIdx.x;                // 0..3071
  const int tid = threadIdx.x;
  const float* src; unsigned short* dst; int R, C, rt, ct;
  const int arr = tb >> 10;                 // 0:wg 1:wu 2:wd (1024 tiles each)
  const int rem = tb & 1023;
  const int e  = rem >> 6;                  // 64 tiles/expert
  const int t2 = rem & 63;
  if (arr == 0)      { src = wg; dst = wgb; R = Hd; C = Id; rt = t2 >> 3; ct = t2 & 7;  }
  else if (arr == 1) { src = wu; dst = wub; R = Hd; C = Id; rt = t2 >> 3; ct = t2 & 7;  }
  else               { src = wd; dst = wdb; R = Id; C = Hd; rt = t2 >> 4; ct = t2 & 15; }
  const int r0 = rt * 128, c0 = ct * 64;
  const float* s = src + (size_t)e * R * C;
  unsigned short* d = dst + (size_t)e * R * C;
  const int r_idx = tid >> 4;               // 16 r-blocks x 8 rows = 128 rows
  const int c_idx = tid & 15;               // 16 c-blocks x 4 cols = 64 cols
  const int rr = r0 + r_idx * 8;
  const int cc = c0 + c_idx * 4;
  uint4 u[8];
  #pragma unroll
  for (int p = 0; p < 8; ++p)
    u[p] = *(const uint4*)(s + (size_t)(rr + p)*C + cc);
  uint4 o;
  o.x = bfpack(u[1].x, u[0].x); o.y = bfpack(u[3].x, u[2].x);
  o.z = bfpack(u[5].x, u[4].x); o.w = bfpack(u[7].x, u[6].x);
  *(uint4*)(d + (size_t)(cc + 0)*R + rr) = o;
  o.x = bfpack(u[1].y, u[0].y); o.y = bfpack(u[3].y, u[2].y);
  o.z = bfpack(u[5].y, u[4].y); o.w = bfpack(u[7].y, u[6].y);
  *(uint4*)(d + (size_t)(cc + 1)*R + rr) = o;
  o.x = bfpack(u[1].z, u[0].z); o.y = bfpack(u[3].z, u[2].z);
  o.z = bfpack(u[5].z, u[4].z); o.w = bfpack(u[7].z, u[6].z);
  *(uint4*)(d + (size_t)(cc + 2)*R + rr) = o;
  o.x = bfpack(u[1].w, u[0].w); o.y = bfpack(u[3].w, u[2].w);
  o.z = bfpack(u[5].w, u[4].w); o.w = bfpack(u[7].w, u[6].w);
  *(uint4*)(d + (size_t)(cc + 3)*R + rr) = o;
}

// ---------------- softmax + bias + top-4 + direct row scatter + (out = zw*x) ----------------
__global__ __launch_bounds__(256) void topk_kernel(
    const float* __restrict__ logits, const float* __restrict__ bias,
    const float* __restrict__ x,
    int* __restrict__ cursors, int* __restrict__ rowmap, float* __restrict__ roww,
    float* __restrict__ out){
  __shared__ float szw[8];
  const int tid = threadIdx.x;
  if (tid < 8){
    const int t = blockIdx.x * 8 + tid;
    float sc[32], bsc[32];
    #pragma unroll
    for (int i = 0; i < 32; i += 4){
      float4 v = *(const float4*)(logits + (size_t)t*NSLOT + i);
      sc[i] = v.x; sc[i+1] = v.y; sc[i+2] = v.z; sc[i+3] = v.w;
    }
    float mx = sc[0];
    #pragma unroll
    for (int i = 1; i < 32; ++i) mx = fmaxf(mx, sc[i]);
    float sum = 0.f;
    #pragma unroll
    for (int i = 0; i < 32; ++i){ sc[i] = __expf(sc[i]-mx); sum += sc[i]; }
    float inv = 1.f / sum;
    #pragma unroll
    for (int i = 0; i < 32; ++i){ sc[i] *= inv; bsc[i] = sc[i] + bias[i]; }
    unsigned int chosen = 0;
    float zw = 0.f;
    #pragma unroll
    for (int k = 0; k < TOPK; ++k){
      float bv = -1e30f, bw = 0.f; int best = 0;
      #pragma unroll
      for (int i = 0; i < 32; ++i){
        float v = ((chosen >> i) & 1u) ? -1e30f : bsc[i];
        if (v > bv){ bv = v; best = i; bw = sc[i]; }
      }
      chosen |= (1u << best);
      if (best < NE){
        int pos = atomicAdd(&cursors[best], 1);
        rowmap[best*ECAP + pos] = t;
        roww[best*ECAP + pos]   = bw;
      } else zw += bw;
    }
    szw[tid] = zw;
  }
  __syncthreads();
  const int lane = tid & 63, wid = tid >> 6;
  const size_t base = (size_t)blockIdx.x * 8 * Hd;
  #pragma unroll
  for (int r0 = 0; r0 < 8; r0 += 4){
    int r = r0 + wid;
    float s = szw[r];
    const float4* xs = (const float4*)(x + base + (size_t)r*Hd);
    float4* os = (float4*)(out + base + (size_t)r*Hd);
    #pragma unroll
    for (int q = 0; q < 4; ++q){
      float4 v = xs[lane + q*64];
      float4 o; o.x = v.x*s; o.y = v.y*s; o.z = v.z*s; o.w = v.w*s;
      os[lane + q*64] = o;
    }
  }
}

// Map linear tile -> (expert, row-base e*ECAP, rows ne, m0). False if out of range.
static __device__ __forceinline__ bool tile_map(const int* __restrict__ counts, int tile,
                                                int& e, int& off, int& ne, int& m0){
  int cumT = 0; e = -1; ne = 0; m0 = 0;
  #pragma unroll
  for (int ee = 0; ee < NE; ++ee){
    int c = counts[ee];
    int nt = (c + 127) >> 7;
    bool here = (e < 0) && (tile < cumT + nt);
    if (here){ e = ee; ne = c; m0 = (tile - cumT) * 128; }
    cumT += nt;
  }
  off = (e >= 0) ? e * ECAP : 0;
  return e >= 0;
}

// ---------------- fused gate+up GEMM + SwiGLU (128x128, dbuf, glds) ----------------
// (256,2): 128 AGPR acc + ~90 VGPR ~ 220 regs/wave; 3 waves/SIMD cap=170 -> SPILLS
// (round-3 regression: WRITE_SIZE 243MB). Do not raise.
__global__ __launch_bounds__(256, 2) void gateup_kernel(
    const unsigned short* __restrict__ xb,
    const unsigned short* __restrict__ wgb,
    const unsigned short* __restrict__ wub,
    const int* __restrict__ counts,
    const int* __restrict__ rowmap,
    const float* __restrict__ roww,
    unsigned short* __restrict__ act){
  const int b = blockIdx.x;
  int e, off, ne, m0;
  if (!tile_map(counts, b >> 2, e, off, ne, m0)) return;
  const int n0 = (b & 3) * 128;

  __shared__ unsigned short sA [2][128*32];
  __shared__ unsigned short sBg[2][128*32];
  __shared__ unsigned short sBu[2][128*32];
  __shared__ int sT[128];

  const int tid = threadIdx.x, lane = tid & 63, wid = tid >> 6;
  if (tid < 128){ int r = m0 + tid; sT[tid] = rowmap[off + ((r < ne) ? r : 0)]; }
  __syncthreads();

  const int r_in = lane >> 2, seg = lane & 3;
  const int rt0 = wid*32 + r_in, rt1 = rt0 + 16;
  const size_t wbase = (size_t)e * Id * Hd;

  const unsigned short* pA0 = xb + (size_t)sT[rt0]*Hd + seg*8;
  const unsigned short* pA1 = xb + (size_t)sT[rt1]*Hd + seg*8;
  const unsigned short* pG0 = wgb + wbase + (size_t)(n0+rt0)*Hd + seg*8;
  const unsigned short* pG1 = wgb + wbase + (size_t)(n0+rt1)*Hd + seg*8;
  const unsigned short* pU0 = wub + wbase + (size_t)(n0+rt0)*Hd + seg*8;
  const unsigned short* pU1 = wub + wbase + (size_t)(n0+rt1)*Hd + seg*8;
  const int dA0 = wid*1024, dA1 = wid*1024 + 512;

  floatx4 accg[4][4], accu[4][4];
  #pragma unroll
  for (int i = 0; i < 4; ++i)
    #pragma unroll
    for (int j = 0; j < 4; ++j){
      floatx4 z = {0.f,0.f,0.f,0.f};
      accg[i][j] = z; accu[i][j] = z;
    }
  const int wm = (wid & 1) * 64, wn = (wid >> 1) * 64;
  const int fm = lane & 15, fq = lane >> 4;

  load_lds16(pA0, &sA[0][dA0]);  load_lds16(pA1, &sA[0][dA1]);
  load_lds16(pG0, &sBg[0][dA0]); load_lds16(pG1, &sBg[0][dA1]);
  load_lds16(pU0, &sBu[0][dA0]); load_lds16(pU1, &sBu[0][dA1]);

  #pragma unroll 2
  for (int kit = 0; kit < 32; ++kit){
    const int cur = kit & 1;
    if (kit < 31){
      const int nk = (kit+1)*32;
      const int nb = 1 - cur;
      load_lds16(pA0 + nk, &sA[nb][dA0]);  load_lds16(pA1 + nk, &sA[nb][dA1]);
      load_lds16(pG0 + nk, &sBg[nb][dA0]); load_lds16(pG1 + nk, &sBg[nb][dA1]);
      load_lds16(pU0 + nk, &sBu[nb][dA0]); load_lds16(pU1 + nk, &sBu[nb][dA1]);
      WAIT_VM(6);
    } else {
      WAIT_VM(0);
    }
    wg_barrier();
    bf16x8 av[4], bgv[4], buv[4];
    #pragma unroll
    for (int i = 0; i < 4; ++i)
      av[i] = *(const bf16x8*)(&sA[cur][(wm + i*16 + fm)*32 + fq*8]);
    #pragma unroll
    for (int j = 0; j < 4; ++j){
      bgv[j] = *(const bf16x8*)(&sBg[cur][(wn + j*16 + fm)*32 + fq*8]);
      buv[j] = *(const bf16x8*)(&sBu[cur][(wn + j*16 + fm)*32 + fq*8]);
    }
    #pragma unroll
    for (int i = 0; i < 4; ++i)
      #pragma unroll
      for (int j = 0; j < 4; ++j){
        accg[i][j] = __builtin_amdgcn_mfma_f32_16x16x32_bf16(av[i], bgv[j], accg[i][j], 0, 0, 0);
        accu[i][j] = __builtin_amdgcn_mfma_f32_16x16x32_bf16(av[i], buv[j], accu[i][j], 0, 0, 0);
      }
    wg_barrier();
  }

  #pragma unroll
  for (int i = 0; i < 4; ++i){
    #pragma unroll
    for (int r = 0; r < 4; ++r){
      int row = wm + i*16 + fq*4 + r;
      if (m0 + row < ne){
        float w = roww[off + m0 + row];
        size_t rb = (size_t)(off + m0 + row) * Id + n0;
        #pragma unroll
        for (int j = 0; j < 4; ++j){
          float g = accg[i][j][r];
          float u = accu[i][j][r];
          float a = (g / (1.f + __expf(-g))) * u * w;
          act[rb + wn + j*16 + fm] = f2bf(a);
        }
      }
    }
  }
}

// ---------------- down GEMM + atomic scatter (dbuf, glds) ----------------
// (256,4): 64 AGPR acc + ~60 VGPR = 124 <= 128 cap -> no spill.
// R8 post-mortem: split-K x2 REGRESSED 44->67 us (WRITE_SIZE doubled 33->66 MB: two
// atomic RMW passes per output line). down is atomic/write-path bound, not occupancy
// bound. Reverted to R5 form. Do not split K.
__global__ __launch_bounds__(256, 4) void down_kernel(
    const unsigned short* __restrict__ act,
    const unsigned short* __restrict__ wdb,
    const int* __restrict__ counts,
    const int* __restrict__ rowmap,
    float* __restrict__ out){
  const int b = blockIdx.x;
  int e, off, ne, m0;
  if (!tile_map(counts, b >> 3, e, off, ne, m0)) return;
  const int n0 = (b & 7) * 128;

  __shared__ unsigned short sA[2][128*32];
  __shared__ unsigned short sB[2][128*32];
  __shared__ int sT[128];

  const int tid = threadIdx.x, lane = tid & 63, wid = tid >> 6;
  if (tid < 128){ int r = m0 + tid; sT[tid] = (r < ne) ? rowmap[off + r] : 0; }

  const int r_in = lane >> 2, seg = lane & 3;
  const int rt0 = wid*32 + r_in, rt1 = rt0 + 16;
  const int gr0 = off + ((m0 + rt0 < ne) ? (m0 + rt0) : 0);
  const int gr1 = off + ((m0 + rt1 < ne) ? (m0 + rt1) : 0);
  const size_t wbase = (size_t)e * Hd * Id;
  const unsigned short* pA0 = act + (size_t)gr0*Id + seg*8;
  const unsigned short* pA1 = act + (size_t)gr1*Id + seg*8;
  const unsigned short* pB0 = wdb + wbase + (size_t)(n0+rt0)*Id + seg*8;
  const unsigned short* pB1 = wdb + wbase + (size_t)(n0+rt1)*Id + seg*8;
  const int dA0 = wid*1024, dA1 = wid*1024 + 512;

  floatx4 acc[4][4];
  #pragma unroll
  for (int i = 0; i < 4; ++i)
    #pragma unroll
    for (int j = 0; j < 4; ++j){ floatx4 z = {0.f,0.f,0.f,0.f}; acc[i][j] = z; }
  const int wm = (wid & 1) * 64, wn = (wid >> 1) * 64;
  const int fm = lane & 15, fq = lane >> 4;

  load_lds16(pA0, &sA[0][dA0]); load_lds16(pA1, &sA[0][dA1]);
  load_lds16(pB0, &sB[0][dA0]); load_lds16(pB1, &sB[0][dA1]);

  #pragma unroll 2
  for (int kit = 0; kit < 16; ++kit){
    const int cur = kit & 1;
    if (kit < 15){
      const int nk = (kit+1)*32;
      const int nb = 1 - cur;
      load_lds16(pA0 + nk, &sA[nb][dA0]); load_lds16(pA1 + nk, &sA[nb][dA1]);
      load_lds16(pB0 + nk, &sB[nb][dA0]); load_lds16(pB1 + nk, &sB[nb][dA1]);
      WAIT_VM(4);
    } else {
      WAIT_VM(0);
    }
    wg_barrier();
    bf16x8 av[4], bv[4];
    #pragma unroll
    for (int i = 0; i < 4; ++i) av[i] = *(const bf16x8*)(&sA[cur][(wm + i*16 + fm)*32 + fq*8]);
    #pragma unroll
    for (int j = 0; j < 4; ++j) bv[j] = *(const bf16x8*)(&sB[cur][(wn + j*16 + fm)*32 + fq*8]);
    #pragma unroll
    for (int i = 0; i < 4; ++i)
      #pragma unroll
      for (int j = 0; j < 4; ++j)
        acc[i][j] = __builtin_amdgcn_mfma_f32_16x16x32_bf16(av[i], bv[j], acc[i][j], 0, 0, 0);
    wg_barrier();
  }

  #pragma unroll
  for (int i = 0; i < 4; ++i){
    #pragma unroll
    for (int r = 0; r < 4; ++r){
      int row = wm + i*16 + fq*4 + r;
      if (m0 + row < ne){
        int t = sT[row];
        #pragma unroll
        for (int j = 0; j < 4; ++j)
          atomicAdd(&out[(size_t)t*Hd + n0 + wn + j*16 + fm], acc[i][j][r]);
      }
    }
  }
}

// =================================================================
extern "C" void kernel_launch(void* const* d_in, const int* in_sizes, int n_in,
                              void* d_out, int out_size, void* d_ws, size_t ws_size,
                              hipStream_t stream){
  (void)in_sizes; (void)n_in; (void)out_size; (void)ws_size;
  const float* x    = (const float*)d_in[0];
  const float* rw   = (const float*)d_in[1];
  const float* bias = (const float*)d_in[2];
  const float* wg   = (const float*)d_in[3];
  const float* wu   = (const float*)d_in[4];
  const float* wd   = (const float*)d_in[5];
  float* out = (float*)d_out;

  char* ws = (char*)d_ws;
  const size_t WSZ = (size_t)NE * Id * Hd * 2;
  unsigned short* wgb = (unsigned short*)(ws);
  unsigned short* wub = (unsigned short*)(ws + WSZ);
  unsigned short* wdb = (unsigned short*)(ws + 2*WSZ);
  unsigned short* xb  = (unsigned short*)(ws + 3*WSZ);
  unsigned short* act = (unsigned short*)(ws + 3*WSZ + (size_t)T_TOK*Hd*2);
  char* misc = ws + 3*WSZ + (size_t)T_TOK*Hd*2 + (size_t)NE*ECAP*Id*2;

  const size_t LOGB = (size_t)T_TOK * NSLOT * 4;
  float* logits  = (float*)misc;
  int*   cursors = (int*)(misc + LOGB);
  char* p2 = misc + LOGB + 256;
  int*   rowmap = (int*)p2;                     p2 += (size_t)NE*ECAP*4;
  float* roww   = (float*)p2;

  router_kernel<<<T_TOK/8, 256, 0, stream>>>(x, rw, xb, logits, cursors);
  transpose_kernel<<<3072, 256, 0, stream>>>(wg, wu, wd, wgb, wub, wdb);
  topk_kernel<<<T_TOK/8, 256, 0, stream>>>(logits, bias, x, cursors, rowmap, roww, out);
  gateup_kernel<<<MAXT*4, 256, 0, stream>>>(xb, wgb, wub, cursors, rowmap, roww, act);
  down_kernel<<<MAXT*8, 256, 0, stream>>>(act, wdb, cursors, rowmap, out);
}